// Round 6
// baseline (1070.898 us; speedup 1.0000x reference)
//
#include <hip/hip_runtime.h>

#define N_NODES 100000
#define N_EDGES 1200000
#define D 64
#define KEEP_PROB 0.7f
#define INV_KEEP (1.0f / KEEP_PROB)
#define NBUCK 1564         // ceil(N_NODES / 64) row-range buckets (row >> 6)
#define PPART 256          // partition/hist blocks (contiguous chunks)
#define CHUNK4 1172        // ceil((N_EDGES/4) / PPART) int4-edges per block

#define ALOAD_I(p)   __hip_atomic_load((p), __ATOMIC_RELAXED, __HIP_MEMORY_SCOPE_AGENT)
#define ALOAD_U64(p) __hip_atomic_load((p), __ATOMIC_RELAXED, __HIP_MEMORY_SCOPE_AGENT)

// ---------------------------------------------------------------------------
__global__ __launch_bounds__(256) void zero_kernel(float4* __restrict__ p, int n4) {
    int i = blockIdx.x * 256 + threadIdx.x;
    if (i < n4) p[i] = make_float4(0.f, 0.f, 0.f, 0.f);
}
__global__ __launch_bounds__(256) void zero_ints_kernel(int* __restrict__ p, int n) {
    int i = blockIdx.x * 256 + threadIdx.x;
    if (i < n) p[i] = 0;
}

// ---------------------------------------------------------------------------
// Build 1: per-bucket counts via per-block LDS histogram over CONTIGUOUS
// chunks (same decomposition as partition_kernel). Persists per-block counts
// h[p][b] so partition can run atomic-free with deterministic bases.
__global__ __launch_bounds__(256) void bucket_hist_kernel(const int4* __restrict__ rows4,
                                                          int* __restrict__ bcnt,
                                                          int* __restrict__ h) {
    __shared__ int hh[NBUCK];
    int p = blockIdx.x;
    int t = threadIdx.x;
    for (int i = t; i < NBUCK; i += 256) hh[i] = 0;
    __syncthreads();
    int i0 = p * CHUNK4;
    int i1 = i0 + CHUNK4;
    if (i1 > N_EDGES / 4) i1 = N_EDGES / 4;
    for (int i = i0 + t; i < i1; i += 256) {
        int4 r = rows4[i];
        atomicAdd(&hh[r.x >> 6], 1);
        atomicAdd(&hh[r.y >> 6], 1);
        atomicAdd(&hh[r.z >> 6], 1);
        atomicAdd(&hh[r.w >> 6], 1);
    }
    __syncthreads();
    int* hp = h + p * NBUCK;
    for (int i = t; i < NBUCK; i += 256) {
        int c = hh[i];
        hp[i] = c;                            // coalesced per-block row
        if (c) atomicAdd(&bcnt[i << 4], c);   // 64B-strided totals for scan
    }
}

// ---------------------------------------------------------------------------
// Build 2: single-block exclusive scan of NBUCK strided counts -> bbase.
__global__ __launch_bounds__(256) void bucket_scan_kernel(const int* __restrict__ bcnt,
                                                          int* __restrict__ bbase) {
    __shared__ int part[256];
    const int CH = 7;   // 256*7 = 1792 >= NBUCK
    int t = threadIdx.x;
    int e[CH]; int s = 0;
    #pragma unroll
    for (int k = 0; k < CH; ++k) {
        int j = t * CH + k;
        e[k] = (j < NBUCK) ? ALOAD_I(&bcnt[j << 4]) : 0;
        s += e[k];
    }
    part[t] = s;
    __syncthreads();
    for (int d = 1; d < 256; d <<= 1) {
        int w = (t >= d) ? part[t - d] : 0;
        __syncthreads();
        part[t] += w;
        __syncthreads();
    }
    int run = part[t] - s;
    #pragma unroll
    for (int k = 0; k < CH; ++k) {
        int j = t * CH + k;
        if (j < NBUCK) { bbase[j] = run; run += e[k]; }
    }
    if (t == 255) bbase[NBUCK] = run;            // == N_EDGES
}

// ---------------------------------------------------------------------------
// Build 2.5: convert h[p][b] counts into per-(block,bucket) global bases:
// h[p][b] <- bbase[b] + sum_{q<p} h[q][b]. One thread per bucket; coalesced.
__global__ __launch_bounds__(256) void rebase_kernel(int* __restrict__ h,
                                                     const int* __restrict__ bbase) {
    int b = blockIdx.x * 256 + threadIdx.x;
    if (b >= NBUCK) return;
    int run = bbase[b];
    for (int p = 0; p < PPART; ++p) {
        int idx = p * NBUCK + b;
        int c = h[idx];
        h[idx] = run;
        run += c;
    }
}

// ---------------------------------------------------------------------------
// Build 3: partition edges into buckets, writing FINAL-format records:
// (col | lr<<17, v0, col | lr<<17, v1) — lr = row & 63 packed into the col
// word (col < 2^17). No row-sort needed downstream (LDS-accumulator SpMM),
// so the old finalize pass is eliminated. Atomic-free: per-block reserved
// runs via LDS cursors (deterministic bases from rebase).
__global__ __launch_bounds__(256) void partition_kernel(
    const int4*   __restrict__ rows4,
    const int4*   __restrict__ cols4,
    const float4* __restrict__ vals4,
    const float4* __restrict__ u04,
    const float4* __restrict__ u14,
    const int*    __restrict__ h,
    uint4*        __restrict__ edata) {
    __shared__ int cur[NBUCK];
    int p = blockIdx.x;
    int t = threadIdx.x;
    const int* hp = h + p * NBUCK;
    for (int i = t; i < NBUCK; i += 256) cur[i] = hp[i];
    __syncthreads();

    int i0 = p * CHUNK4;
    int i1 = i0 + CHUNK4;
    if (i1 > N_EDGES / 4) i1 = N_EDGES / 4;
    for (int i = i0 + t; i < i1; i += 256) {
        int4   r  = rows4[i];
        int4   c  = cols4[i];
        float4 v  = vals4[i];
        float4 u0 = u04[i];
        float4 u1 = u14[i];

        int p0 = atomicAdd(&cur[r.x >> 6], 1);
        int p1 = atomicAdd(&cur[r.y >> 6], 1);
        int p2 = atomicAdd(&cur[r.z >> 6], 1);
        int p3 = atomicAdd(&cur[r.w >> 6], 1);

        uint4 rec; float vv; unsigned cr;
        vv = v.x * INV_KEEP;
        cr = (unsigned)c.x | (((unsigned)r.x & 63u) << 17);
        rec.x = cr;
        rec.y = __float_as_uint((u0.x + KEEP_PROB >= 1.0f) ? vv : 0.f);
        rec.z = cr;
        rec.w = __float_as_uint((u1.x + KEEP_PROB >= 1.0f) ? vv : 0.f);
        edata[p0] = rec;
        vv = v.y * INV_KEEP;
        cr = (unsigned)c.y | (((unsigned)r.y & 63u) << 17);
        rec.x = cr;
        rec.y = __float_as_uint((u0.y + KEEP_PROB >= 1.0f) ? vv : 0.f);
        rec.z = cr;
        rec.w = __float_as_uint((u1.y + KEEP_PROB >= 1.0f) ? vv : 0.f);
        edata[p1] = rec;
        vv = v.z * INV_KEEP;
        cr = (unsigned)c.z | (((unsigned)r.z & 63u) << 17);
        rec.x = cr;
        rec.y = __float_as_uint((u0.z + KEEP_PROB >= 1.0f) ? vv : 0.f);
        rec.z = cr;
        rec.w = __float_as_uint((u1.z + KEEP_PROB >= 1.0f) ? vv : 0.f);
        edata[p2] = rec;
        vv = v.w * INV_KEEP;
        cr = (unsigned)c.w | (((unsigned)r.w & 63u) << 17);
        rec.x = cr;
        rec.y = __float_as_uint((u0.w + KEEP_PROB >= 1.0f) ? vv : 0.f);
        rec.z = cr;
        rec.w = __float_as_uint((u1.w + KEEP_PROB >= 1.0f) ? vv : 0.f);
        edata[p3] = rec;
    }
}

// ---------------------------------------------------------------------------
// SpMM, bucket-LDS-accumulator form: one block per bucket (64 rows).
// Edges split flat & balanced across 16 lane-groups (±1 edge) -> zero
// divergence waste (old gather looped to max of 4 Poisson rows, ~40% extra).
// Branch-free inner loop: rec -> 16B x-gather -> 4 LDS atomicAdd
// (native ds_add_f32). Slot swizzle (j + lr) & 63: float4-granular layout
// would put all 64 lanes in 8 banks (8-way); swizzle makes each group
// 2-way (free) and decorrelates the 4 groups by row.
__global__ __launch_bounds__(256) void spmm_bucket_kernel(
    const float4* __restrict__ x_in,
    const unsigned long long* __restrict__ edata,
    const int*   __restrict__ bbase,
    float4*      __restrict__ io,
    int layer) {
    __shared__ float accs[64 * 64];   // 16 KB: [lr][slot], slot = (j+lr)&63
    int b = blockIdx.x;
    int t = threadIdx.x;
    int base = bbase[b];
    int size = bbase[b + 1] - base;
    int row0 = b << 6;

    #pragma unroll
    for (int i = 0; i < 4; ++i)
        *(float4*)&accs[(i * 256 + t) * 4] = make_float4(0.f, 0.f, 0.f, 0.f);
    __syncthreads();

    int g   = t >> 4;                 // lane-group 0..15
    int l16 = t & 15;
    int e0 = base + ((size * g) >> 4);
    int e1 = base + ((size * (g + 1)) >> 4);
    int j0 = l16 << 2;

    #pragma unroll 8
    for (int e = e0; e < e1; ++e) {
        unsigned long long rec = ALOAD_U64(&edata[2 * e + layer]);
        unsigned lo = (unsigned)rec;
        float v = __uint_as_float((unsigned)(rec >> 32));
        int c  = (int)(lo & 0x1ffffu);
        int lr = (int)(lo >> 17);
        int cc = (v != 0.f) ? c : 0;          // dropped edges -> hot row 0
        float4 x = x_in[(cc << 4) + l16];
        float* arow = &accs[lr << 6];
        atomicAdd(&arow[(j0 + 0 + lr) & 63], v * x.x);
        atomicAdd(&arow[(j0 + 1 + lr) & 63], v * x.y);
        atomicAdd(&arow[(j0 + 2 + lr) & 63], v * x.z);
        atomicAdd(&arow[(j0 + 3 + lr) & 63], v * x.w);
    }
    __syncthreads();

    // writeback with unswizzle: granule gg of row lr lives at slots
    // (4*gg+lr)&63 .. +3 (consecutive mod 64).
    #pragma unroll
    for (int i = 0; i < 4; ++i) {
        int idx = i * 256 + t;        // 0..1023 output granules
        int lr = idx >> 4;
        int gg = idx & 15;
        int row = row0 + lr;
        if (row < N_NODES) {
            const float* arow = &accs[lr << 6];
            int s0 = (gg * 4 + lr) & 63;
            float4 sv;
            sv.x = arow[s0];
            sv.y = arow[(s0 + 1) & 63];
            sv.z = arow[(s0 + 2) & 63];
            sv.w = arow[(s0 + 3) & 63];
            int o = (row << 4) + gg;
            if (layer == 0) {
                io[o] = sv;
            } else {
                float4 p = io[o];
                p.x = (p.x + sv.x) * (1.0f / 3.0f);
                p.y = (p.y + sv.y) * (1.0f / 3.0f);
                p.z = (p.z + sv.z) * (1.0f / 3.0f);
                p.w = (p.w + sv.w) * (1.0f / 3.0f);
                io[o] = p;
            }
        }
    }
}

// ---------------------------------------------------------------------------
// out[n,j] = b[j] + sum_k emb[n,k]*W[j,k] + x1[n,j]
// Register-blocked: 64 nodes/block, 4x4 tile/thread; launch_bounds(256,4)
// caps VGPR at 128 (R3 lesson: full unroll blew to 240 -> 8.8% occupancy).
#define FMA4(A, E, WV) \
    A.x = fmaf(E, WV.x, A.x); A.y = fmaf(E, WV.y, A.y); \
    A.z = fmaf(E, WV.z, A.z); A.w = fmaf(E, WV.w, A.w);

__global__ __launch_bounds__(256, 4) void fc_add_kernel(
    const float* __restrict__ emb,
    const float* __restrict__ W,
    const float* __restrict__ b,
    const float* __restrict__ x1,
    float*       __restrict__ out) {
    __shared__ float Wt[D * 68];    // Wt[k][j] = W[j][k], row pad 68
    __shared__ float Es[64 * 68];   // Es[n][k],           row pad 68

    int t = threadIdx.x;
    int n0 = blockIdx.x * 64;

    #pragma unroll
    for (int i = 0; i < 16; ++i) {
        int idx = i * 256 + t;          // = j*64 + k
        Wt[(idx & 63) * 68 + (idx >> 6)] = W[idx];
    }
    #pragma unroll
    for (int i = 0; i < 4; ++i) {
        int idx4 = i * 256 + t;
        int n = idx4 >> 4;              // 0..63
        int k0 = (idx4 & 15) * 4;
        float4 v = make_float4(0.f, 0.f, 0.f, 0.f);
        if (n0 + n < N_NODES) v = *(const float4*)&emb[(n0 + n) * D + k0];
        *(float4*)&Es[n * 68 + k0] = v;
    }
    __syncthreads();

    int tj = t & 15;                    // j-group: j0 = 4*tj
    int tn = t >> 4;                    // node-group: nodes 4*tn .. 4*tn+3
    int j0 = tj * 4;

    float4 bb = *(const float4*)&b[j0];
    float4 acc[4];
    #pragma unroll
    for (int i = 0; i < 4; ++i) acc[i] = bb;

    const float* es = &Es[(tn * 4) * 68];
    #pragma unroll 4
    for (int kc = 0; kc < 16; ++kc) {
        int k = kc * 4;
        float4 w0 = *(const float4*)&Wt[(k + 0) * 68 + j0];
        float4 w1 = *(const float4*)&Wt[(k + 1) * 68 + j0];
        float4 w2 = *(const float4*)&Wt[(k + 2) * 68 + j0];
        float4 w3 = *(const float4*)&Wt[(k + 3) * 68 + j0];
        float4 e0 = *(const float4*)&es[0 * 68 + k];
        float4 e1 = *(const float4*)&es[1 * 68 + k];
        float4 e2 = *(const float4*)&es[2 * 68 + k];
        float4 e3 = *(const float4*)&es[3 * 68 + k];
        FMA4(acc[0], e0.x, w0); FMA4(acc[0], e0.y, w1);
        FMA4(acc[0], e0.z, w2); FMA4(acc[0], e0.w, w3);
        FMA4(acc[1], e1.x, w0); FMA4(acc[1], e1.y, w1);
        FMA4(acc[1], e1.z, w2); FMA4(acc[1], e1.w, w3);
        FMA4(acc[2], e2.x, w0); FMA4(acc[2], e2.y, w1);
        FMA4(acc[2], e2.z, w2); FMA4(acc[2], e2.w, w3);
        FMA4(acc[3], e3.x, w0); FMA4(acc[3], e3.y, w1);
        FMA4(acc[3], e3.z, w2); FMA4(acc[3], e3.w, w3);
    }

    #pragma unroll
    for (int i = 0; i < 4; ++i) {
        int n = n0 + tn * 4 + i;
        if (n < N_NODES) {
            float4 p = *(const float4*)&x1[n * D + j0];
            float4 a = acc[i];
            a.x += p.x; a.y += p.y; a.z += p.z; a.w += p.w;
            *(float4*)&out[n * D + j0] = a;
        }
    }
}

// ---------------------------------------------------------------------------
// Fallback (atomic path, replay-proven) if ws too small
__global__ __launch_bounds__(256) void spmm_atomic_kernel(
    const float* __restrict__ x_in,
    const float* __restrict__ vals,
    const float* __restrict__ drop_u,
    const int*   __restrict__ rows,
    const int*   __restrict__ cols,
    float*       __restrict__ x_out) {
    int wave = (blockIdx.x * 256 + threadIdx.x) >> 6;
    int lane = threadIdx.x & 63;
    if (wave >= N_EDGES) return;
    float u = drop_u[wave];
    if (u + KEEP_PROB < 1.0f) return;
    float v = vals[wave] * INV_KEEP;
    atomicAdd(&x_out[rows[wave] * D + lane], v * x_in[cols[wave] * D + lane]);
}

__global__ __launch_bounds__(256) void scale_kernel(float4* __restrict__ p, int n4) {
    int i = blockIdx.x * 256 + threadIdx.x;
    if (i < n4) {
        float4 v = p[i];
        v.x *= (1.f/3.f); v.y *= (1.f/3.f); v.z *= (1.f/3.f); v.w *= (1.f/3.f);
        p[i] = v;
    }
}

// ---------------------------------------------------------------------------
extern "C" void kernel_launch(void* const* d_in, const int* in_sizes, int n_in,
                              void* d_out, int out_size, void* d_ws, size_t ws_size,
                              hipStream_t stream) {
    const float* all_emb = (const float*)d_in[0];
    const float* W       = (const float*)d_in[1];
    const float* b       = (const float*)d_in[2];
    const float* vals    = (const float*)d_in[3];
    const float* drop_u  = (const float*)d_in[4];   // [2, E]
    const int*   rows    = (const int*)d_in[5];
    const int*   cols    = (const int*)d_in[6];

    float* out = (float*)d_out;

    // workspace layout (offsets kept from prior rounds; Pstart slot unused now)
    char* ws = (char*)d_ws;
    float* x1     = (float*)(ws);                   // 25,600,000 B
    uint4* edata  = (uint4*)(ws + 26000064);        // 19,200,000 B
    int*   bcnt   = (int*)  (ws + 45200064);        //    100,096 B (NBUCK x 64B)
    int*   bbase  = (int*)  (ws + 45300160);        //      6,272 B (NBUCK+1)
    // h[PPART][NBUCK] counts->bases: carved from the x1 region; h is dead
    // before spmm layer 0 overwrites x1. 1,601,536 B @ +19,200,000.
    int*   h      = (int*)  (ws + 19200000);
    const size_t WS_NEEDED = 45406528;

    const int n4 = N_NODES * D / 4;
    const int zb = (n4 + 255) / 256;
    const int fc_blocks = (N_NODES + 63) / 64;            // 1563

    if (ws_size >= WS_NEEDED) {
        zero_ints_kernel<<<(NBUCK * 16 + 255) / 256, 256, 0, stream>>>(bcnt, NBUCK * 16);
        bucket_hist_kernel<<<PPART, 256, 0, stream>>>((const int4*)rows, bcnt, h);
        bucket_scan_kernel<<<1, 256, 0, stream>>>(bcnt, bbase);
        rebase_kernel<<<(NBUCK + 255) / 256, 256, 0, stream>>>(h, bbase);
        partition_kernel<<<PPART, 256, 0, stream>>>(
            (const int4*)rows, (const int4*)cols, (const float4*)vals,
            (const float4*)drop_u, (const float4*)(drop_u + N_EDGES),
            h, edata);
        // layer 0: x1 = A1 @ all_emb
        spmm_bucket_kernel<<<NBUCK, 256, 0, stream>>>(
            (const float4*)all_emb, (const unsigned long long*)edata, bbase,
            (float4*)x1, 0);
        // out = fc(all_emb) + x1
        fc_add_kernel<<<fc_blocks, 256, 0, stream>>>(all_emb, W, b, x1, out);
        // layer 1 (fused /3): out = (out + A2 @ x1) / 3
        spmm_bucket_kernel<<<NBUCK, 256, 0, stream>>>(
            (const float4*)x1, (const unsigned long long*)edata, bbase,
            (float4*)out, 1);
    } else {
        // fallback: proven atomic path
        const int spmm_blocks = (N_EDGES + 3) / 4;
        zero_kernel<<<zb, 256, 0, stream>>>((float4*)x1, n4);
        spmm_atomic_kernel<<<spmm_blocks, 256, 0, stream>>>(all_emb, vals, drop_u,
                                                            rows, cols, x1);
        fc_add_kernel<<<fc_blocks, 256, 0, stream>>>(all_emb, W, b, x1, out);
        spmm_atomic_kernel<<<spmm_blocks, 256, 0, stream>>>(x1, vals,
                                                            drop_u + N_EDGES,
                                                            rows, cols, out);
        scale_kernel<<<zb, 256, 0, stream>>>((float4*)out, n4);
    }
}

// Round 7
// 281.270 us; speedup vs baseline: 3.8074x; 3.8074x over previous
//
#include <hip/hip_runtime.h>

#define N_NODES 100000
#define N_EDGES 1200000
#define D 64
#define KEEP_PROB 0.7f
#define INV_KEEP (1.0f / KEEP_PROB)
#define NBUCK 1564         // ceil(N_NODES / 64) row-range buckets (row >> 6)
#define MAXB 1024          // finalize LDS record capacity (mean ~767)
#define PPART 256          // partition/hist blocks (contiguous chunks)
#define CHUNK4 1172        // ceil((N_EDGES/4) / PPART) int4-edges per block

#define ALOAD_I(p)   __hip_atomic_load((p), __ATOMIC_RELAXED, __HIP_MEMORY_SCOPE_AGENT)
#define ALOAD_U64(p) __hip_atomic_load((p), __ATOMIC_RELAXED, __HIP_MEMORY_SCOPE_AGENT)

// ---------------------------------------------------------------------------
__global__ __launch_bounds__(256) void zero_kernel(float4* __restrict__ p, int n4) {
    int i = blockIdx.x * 256 + threadIdx.x;
    if (i < n4) p[i] = make_float4(0.f, 0.f, 0.f, 0.f);
}
__global__ __launch_bounds__(256) void zero_ints_kernel(int* __restrict__ p, int n) {
    int i = blockIdx.x * 256 + threadIdx.x;
    if (i < n) p[i] = 0;
}

// ---------------------------------------------------------------------------
// Build 1: per-bucket counts via per-block LDS histogram over CONTIGUOUS
// chunks (same decomposition as partition_kernel). Persists per-block counts
// h[p][b] so partition can run atomic-free with deterministic bases.
__global__ __launch_bounds__(256) void bucket_hist_kernel(const int4* __restrict__ rows4,
                                                          int* __restrict__ bcnt,
                                                          int* __restrict__ h) {
    __shared__ int hh[NBUCK];
    int p = blockIdx.x;
    int t = threadIdx.x;
    for (int i = t; i < NBUCK; i += 256) hh[i] = 0;
    __syncthreads();
    int i0 = p * CHUNK4;
    int i1 = i0 + CHUNK4;
    if (i1 > N_EDGES / 4) i1 = N_EDGES / 4;
    for (int i = i0 + t; i < i1; i += 256) {
        int4 r = rows4[i];
        atomicAdd(&hh[r.x >> 6], 1);
        atomicAdd(&hh[r.y >> 6], 1);
        atomicAdd(&hh[r.z >> 6], 1);
        atomicAdd(&hh[r.w >> 6], 1);
    }
    __syncthreads();
    int* hp = h + p * NBUCK;
    for (int i = t; i < NBUCK; i += 256) {
        int c = hh[i];
        hp[i] = c;                            // coalesced per-block row
        if (c) atomicAdd(&bcnt[i << 4], c);   // 64B-strided totals for scan
    }
}

// ---------------------------------------------------------------------------
// Build 2: single-block exclusive scan of NBUCK strided counts -> bbase.
__global__ __launch_bounds__(256) void bucket_scan_kernel(const int* __restrict__ bcnt,
                                                          int* __restrict__ bbase) {
    __shared__ int part[256];
    const int CH = 7;   // 256*7 = 1792 >= NBUCK
    int t = threadIdx.x;
    int e[CH]; int s = 0;
    #pragma unroll
    for (int k = 0; k < CH; ++k) {
        int j = t * CH + k;
        e[k] = (j < NBUCK) ? ALOAD_I(&bcnt[j << 4]) : 0;
        s += e[k];
    }
    part[t] = s;
    __syncthreads();
    for (int d = 1; d < 256; d <<= 1) {
        int w = (t >= d) ? part[t - d] : 0;
        __syncthreads();
        part[t] += w;
        __syncthreads();
    }
    int run = part[t] - s;
    #pragma unroll
    for (int k = 0; k < CH; ++k) {
        int j = t * CH + k;
        if (j < NBUCK) { bbase[j] = run; run += e[k]; }
    }
    if (t == 255) bbase[NBUCK] = run;            // == N_EDGES
}

// ---------------------------------------------------------------------------
// Build 2.5: convert h[p][b] counts into per-(block,bucket) global bases.
__global__ __launch_bounds__(256) void rebase_kernel(int* __restrict__ h,
                                                     const int* __restrict__ bbase) {
    int b = blockIdx.x * 256 + threadIdx.x;
    if (b >= NBUCK) return;
    int run = bbase[b];
    for (int p = 0; p < PPART; ++p) {
        int idx = p * NBUCK + b;
        int c = h[idx];
        h[idx] = run;
        run += c;
    }
}

// ---------------------------------------------------------------------------
// Build 3: partition edges into buckets (R1/R4-proven). Staging record:
// (col, v0, v1, row). Dropout pre-folded. Atomic-free globally.
__global__ __launch_bounds__(256) void partition_kernel(
    const int4*   __restrict__ rows4,
    const int4*   __restrict__ cols4,
    const float4* __restrict__ vals4,
    const float4* __restrict__ u04,
    const float4* __restrict__ u14,
    const int*    __restrict__ h,
    uint4*        __restrict__ edata) {
    __shared__ int cur[NBUCK];
    int p = blockIdx.x;
    int t = threadIdx.x;
    const int* hp = h + p * NBUCK;
    for (int i = t; i < NBUCK; i += 256) cur[i] = hp[i];
    __syncthreads();

    int i0 = p * CHUNK4;
    int i1 = i0 + CHUNK4;
    if (i1 > N_EDGES / 4) i1 = N_EDGES / 4;
    for (int i = i0 + t; i < i1; i += 256) {
        int4   r  = rows4[i];
        int4   c  = cols4[i];
        float4 v  = vals4[i];
        float4 u0 = u04[i];
        float4 u1 = u14[i];

        int p0 = atomicAdd(&cur[r.x >> 6], 1);
        int p1 = atomicAdd(&cur[r.y >> 6], 1);
        int p2 = atomicAdd(&cur[r.z >> 6], 1);
        int p3 = atomicAdd(&cur[r.w >> 6], 1);

        uint4 rec; float vv;
        vv = v.x * INV_KEEP;
        rec.x = (unsigned)c.x;
        rec.y = __float_as_uint((u0.x + KEEP_PROB >= 1.0f) ? vv : 0.f);
        rec.z = __float_as_uint((u1.x + KEEP_PROB >= 1.0f) ? vv : 0.f);
        rec.w = (unsigned)r.x;
        edata[p0] = rec;
        vv = v.y * INV_KEEP;
        rec.x = (unsigned)c.y;
        rec.y = __float_as_uint((u0.y + KEEP_PROB >= 1.0f) ? vv : 0.f);
        rec.z = __float_as_uint((u1.y + KEEP_PROB >= 1.0f) ? vv : 0.f);
        rec.w = (unsigned)r.y;
        edata[p1] = rec;
        vv = v.z * INV_KEEP;
        rec.x = (unsigned)c.z;
        rec.y = __float_as_uint((u0.z + KEEP_PROB >= 1.0f) ? vv : 0.f);
        rec.z = __float_as_uint((u1.z + KEEP_PROB >= 1.0f) ? vv : 0.f);
        rec.w = (unsigned)r.z;
        edata[p2] = rec;
        vv = v.w * INV_KEEP;
        rec.x = (unsigned)c.w;
        rec.y = __float_as_uint((u0.w + KEEP_PROB >= 1.0f) ? vv : 0.f);
        rec.z = __float_as_uint((u1.w + KEEP_PROB >= 1.0f) ? vv : 0.f);
        rec.w = (unsigned)r.w;
        edata[p3] = rec;
    }
}

// ---------------------------------------------------------------------------
// Build 4 (restored from R4 + lr-pack): one block per bucket (64 rows).
// LDS-sort records by row, write final (col|lr<<17, v0, col|lr<<17, v1)
// records in-place (row-sorted). Overflow spills via scratch.
__global__ __launch_bounds__(256) void finalize_kernel(
    uint4* __restrict__ edata,
    const int* __restrict__ bbase,
    uint4* __restrict__ scratch) {      // x1 region (unwritten at this point)
    __shared__ uint4 recs[MAXB];
    __shared__ int cnt[64], cur[64], part[64];
    int b = blockIdx.x;
    int t = threadIdx.x;
    int base = bbase[b];
    int size = bbase[b + 1] - base;
    bool small = (size <= MAXB);

    const unsigned long long* src = (const unsigned long long*)(edata + base);
    if (small) {
        for (int i = t; i < size; i += 256) {
            unsigned long long lo = ALOAD_U64(src + 2 * i);
            unsigned long long hi = ALOAD_U64(src + 2 * i + 1);
            uint4 r;
            r.x = (unsigned)lo; r.y = (unsigned)(lo >> 32);
            r.z = (unsigned)hi; r.w = (unsigned)(hi >> 32);
            recs[i] = r;
        }
    } else {
        unsigned long long* dst = (unsigned long long*)(scratch + base);
        for (int i = t; i < 2 * size; i += 256) dst[i] = ALOAD_U64(src + i);
    }
    if (t < 64) cnt[t] = 0;
    __syncthreads();

    const uint4* gsrc = scratch + base;
    for (int i = t; i < size; i += 256) {
        unsigned rw = small ? recs[i].w : gsrc[i].w;
        atomicAdd(&cnt[rw & 63], 1);
    }
    __syncthreads();

    int v = (t < 64) ? cnt[t] : 0;
    if (t < 64) part[t] = v;
    __syncthreads();
    for (int d = 1; d < 64; d <<= 1) {
        int w = (t >= d && t < 64) ? part[t - d] : 0;
        __syncthreads();
        if (t < 64) part[t] += w;
        __syncthreads();
    }
    if (t < 64) cur[t] = part[t] - v;
    __syncthreads();

    for (int i = t; i < size; i += 256) {
        uint4 r = small ? recs[i] : gsrc[i];
        unsigned lr = r.w & 63u;
        int slot = atomicAdd(&cur[lr], 1);
        unsigned cr = r.x | (lr << 17);     // pack local row into col word
        uint4 outrec;
        outrec.x = cr; outrec.y = r.y;      // (col|lr, v0,
        outrec.z = cr; outrec.w = r.z;      //  col|lr, v1)
        edata[base + slot] = outrec;
    }
}

// ---------------------------------------------------------------------------
// SpMM, flat-balanced register-accumulation form. One block per bucket
// (64 rows, row-sorted edges). 16 lane-groups each walk a contiguous
// ~1/16 slice of the bucket's edges (±1) -> zero divergence waste
// (old gather looped to max of 4 Poisson(12) rows: ~285 vs 192 wave-iters
// per bucket). Row sums accumulate in a register float4 per lane and are
// PLAIN-stored to the LDS tile on row change — race-free via ownership:
// a row is owned by the group containing its first edge; a group whose
// slice starts mid-row stores that prefix to part[g], merged sequentially
// by 16 lanes after the barrier. NO LDS atomics in the hot loop (R6 lesson:
// per-edge fp LDS atomicAdd measured ~3.6 CU-cyc/lane-op -> 455us/layer).
__global__ __launch_bounds__(256) void spmm_flat_kernel(
    const float4* __restrict__ x_in,
    const unsigned long long* __restrict__ edata,
    const int*   __restrict__ bbase,
    float4*      __restrict__ io,
    int layer) {
    __shared__ float accs[64 * 64];   // 16 KB: [lr][col]
    __shared__ float partb[16][64];   // boundary-prefix partials per group
    __shared__ int   prow[16];
    int b = blockIdx.x;
    int t = threadIdx.x;
    int base = bbase[b];
    int size = bbase[b + 1] - base;
    int row0 = b << 6;

    #pragma unroll
    for (int i = 0; i < 4; ++i)
        *(float4*)&accs[(i * 256 + t) * 4] = make_float4(0.f, 0.f, 0.f, 0.f);
    if (t < 16) prow[t] = -1;
    __syncthreads();

    int g   = t >> 4;                 // lane-group 0..15
    int l16 = t & 15;
    int e0 = base + ((size * g) >> 4);
    int e1 = base + ((size * (g + 1)) >> 4);
    int j0 = l16 << 2;

    // does this slice start mid-row? (prev record has same lr)
    bool partial = false;
    if (e0 < e1 && e0 > base) {
        unsigned plo = (unsigned)ALOAD_U64(&edata[2 * (e0 - 1) + layer]);
        unsigned flo = (unsigned)ALOAD_U64(&edata[2 * e0 + layer]);
        partial = ((plo >> 17) == (flo >> 17));
    }

    float4 acc = make_float4(0.f, 0.f, 0.f, 0.f);
    int cur = -1;
    bool first = true;
    for (int e = e0; e < e1; ++e) {
        unsigned long long rec = ALOAD_U64(&edata[2 * e + layer]);
        unsigned lo = (unsigned)rec;
        float v = __uint_as_float((unsigned)(rec >> 32));
        int lr = (int)(lo >> 17);
        if (lr != cur) {                       // group-uniform branch
            if (cur >= 0) {
                if (first && partial) {
                    *(float4*)&partb[g][j0] = acc;
                    if (l16 == 0) prow[g] = cur;
                } else {
                    *(float4*)&accs[(cur << 6) + j0] = acc;   // owned row
                }
                first = false;
            }
            acc = make_float4(0.f, 0.f, 0.f, 0.f);
            cur = lr;
        }
        int c  = (int)(lo & 0x1ffffu);
        int cc = (v != 0.f) ? c : 0;          // dropped edges -> hot row 0
        float4 x = x_in[(cc << 4) + l16];
        acc.x = fmaf(v, x.x, acc.x);
        acc.y = fmaf(v, x.y, acc.y);
        acc.z = fmaf(v, x.z, acc.z);
        acc.w = fmaf(v, x.w, acc.w);
    }
    if (cur >= 0) {                            // tail flush
        if (first && partial) {
            *(float4*)&partb[g][j0] = acc;
            if (l16 == 0) prow[g] = cur;
        } else {
            *(float4*)&accs[(cur << 6) + j0] = acc;
        }
    }
    __syncthreads();

    // merge boundary partials: 16 lanes, sequential over groups (race-free)
    if (t < 16) {
        int jj = t << 2;
        for (int gg = 1; gg < 16; ++gg) {
            int pr = prow[gg];
            if (pr >= 0) {
                float* a = &accs[(pr << 6) + jj];
                const float* p = &partb[gg][jj];
                a[0] += p[0]; a[1] += p[1]; a[2] += p[2]; a[3] += p[3];
            }
        }
    }
    __syncthreads();

    // writeback: 1024 float4 granules, coalesced
    #pragma unroll
    for (int i = 0; i < 4; ++i) {
        int idx = i * 256 + t;        // 0..1023
        int lr = idx >> 4;
        int gg = idx & 15;
        int row = row0 + lr;
        if (row < N_NODES) {
            float4 sv = *(const float4*)&accs[(lr << 6) + (gg << 2)];
            int o = (row << 4) + gg;
            if (layer == 0) {
                io[o] = sv;
            } else {
                float4 p = io[o];
                p.x = (p.x + sv.x) * (1.0f / 3.0f);
                p.y = (p.y + sv.y) * (1.0f / 3.0f);
                p.z = (p.z + sv.z) * (1.0f / 3.0f);
                p.w = (p.w + sv.w) * (1.0f / 3.0f);
                io[o] = p;
            }
        }
    }
}

// ---------------------------------------------------------------------------
// out[n,j] = b[j] + sum_k emb[n,k]*W[j,k] + x1[n,j]
// Register-blocked: 64 nodes/block, 4x4 tile/thread; launch_bounds(256,4)
// caps VGPR at 128 (R3 lesson: full unroll blew to 240 -> 8.8% occupancy).
#define FMA4(A, E, WV) \
    A.x = fmaf(E, WV.x, A.x); A.y = fmaf(E, WV.y, A.y); \
    A.z = fmaf(E, WV.z, A.z); A.w = fmaf(E, WV.w, A.w);

__global__ __launch_bounds__(256, 4) void fc_add_kernel(
    const float* __restrict__ emb,
    const float* __restrict__ W,
    const float* __restrict__ b,
    const float* __restrict__ x1,
    float*       __restrict__ out) {
    __shared__ float Wt[D * 68];    // Wt[k][j] = W[j][k], row pad 68
    __shared__ float Es[64 * 68];   // Es[n][k],           row pad 68

    int t = threadIdx.x;
    int n0 = blockIdx.x * 64;

    #pragma unroll
    for (int i = 0; i < 16; ++i) {
        int idx = i * 256 + t;          // = j*64 + k
        Wt[(idx & 63) * 68 + (idx >> 6)] = W[idx];
    }
    #pragma unroll
    for (int i = 0; i < 4; ++i) {
        int idx4 = i * 256 + t;
        int n = idx4 >> 4;              // 0..63
        int k0 = (idx4 & 15) * 4;
        float4 v = make_float4(0.f, 0.f, 0.f, 0.f);
        if (n0 + n < N_NODES) v = *(const float4*)&emb[(n0 + n) * D + k0];
        *(float4*)&Es[n * 68 + k0] = v;
    }
    __syncthreads();

    int tj = t & 15;                    // j-group: j0 = 4*tj
    int tn = t >> 4;                    // node-group: nodes 4*tn .. 4*tn+3
    int j0 = tj * 4;

    float4 bb = *(const float4*)&b[j0];
    float4 acc[4];
    #pragma unroll
    for (int i = 0; i < 4; ++i) acc[i] = bb;

    const float* es = &Es[(tn * 4) * 68];
    #pragma unroll 4
    for (int kc = 0; kc < 16; ++kc) {
        int k = kc * 4;
        float4 w0 = *(const float4*)&Wt[(k + 0) * 68 + j0];
        float4 w1 = *(const float4*)&Wt[(k + 1) * 68 + j0];
        float4 w2 = *(const float4*)&Wt[(k + 2) * 68 + j0];
        float4 w3 = *(const float4*)&Wt[(k + 3) * 68 + j0];
        float4 e0 = *(const float4*)&es[0 * 68 + k];
        float4 e1 = *(const float4*)&es[1 * 68 + k];
        float4 e2 = *(const float4*)&es[2 * 68 + k];
        float4 e3 = *(const float4*)&es[3 * 68 + k];
        FMA4(acc[0], e0.x, w0); FMA4(acc[0], e0.y, w1);
        FMA4(acc[0], e0.z, w2); FMA4(acc[0], e0.w, w3);
        FMA4(acc[1], e1.x, w0); FMA4(acc[1], e1.y, w1);
        FMA4(acc[1], e1.z, w2); FMA4(acc[1], e1.w, w3);
        FMA4(acc[2], e2.x, w0); FMA4(acc[2], e2.y, w1);
        FMA4(acc[2], e2.z, w2); FMA4(acc[2], e2.w, w3);
        FMA4(acc[3], e3.x, w0); FMA4(acc[3], e3.y, w1);
        FMA4(acc[3], e3.z, w2); FMA4(acc[3], e3.w, w3);
    }

    #pragma unroll
    for (int i = 0; i < 4; ++i) {
        int n = n0 + tn * 4 + i;
        if (n < N_NODES) {
            float4 p = *(const float4*)&x1[n * D + j0];
            float4 a = acc[i];
            a.x += p.x; a.y += p.y; a.z += p.z; a.w += p.w;
            *(float4*)&out[n * D + j0] = a;
        }
    }
}

// ---------------------------------------------------------------------------
// Fallback (atomic path, replay-proven) if ws too small
__global__ __launch_bounds__(256) void spmm_atomic_kernel(
    const float* __restrict__ x_in,
    const float* __restrict__ vals,
    const float* __restrict__ drop_u,
    const int*   __restrict__ rows,
    const int*   __restrict__ cols,
    float*       __restrict__ x_out) {
    int wave = (blockIdx.x * 256 + threadIdx.x) >> 6;
    int lane = threadIdx.x & 63;
    if (wave >= N_EDGES) return;
    float u = drop_u[wave];
    if (u + KEEP_PROB < 1.0f) return;
    float v = vals[wave] * INV_KEEP;
    atomicAdd(&x_out[rows[wave] * D + lane], v * x_in[cols[wave] * D + lane]);
}

__global__ __launch_bounds__(256) void scale_kernel(float4* __restrict__ p, int n4) {
    int i = blockIdx.x * 256 + threadIdx.x;
    if (i < n4) {
        float4 v = p[i];
        v.x *= (1.f/3.f); v.y *= (1.f/3.f); v.z *= (1.f/3.f); v.w *= (1.f/3.f);
        p[i] = v;
    }
}

// ---------------------------------------------------------------------------
extern "C" void kernel_launch(void* const* d_in, const int* in_sizes, int n_in,
                              void* d_out, int out_size, void* d_ws, size_t ws_size,
                              hipStream_t stream) {
    const float* all_emb = (const float*)d_in[0];
    const float* W       = (const float*)d_in[1];
    const float* b       = (const float*)d_in[2];
    const float* vals    = (const float*)d_in[3];
    const float* drop_u  = (const float*)d_in[4];   // [2, E]
    const int*   rows    = (const int*)d_in[5];
    const int*   cols    = (const int*)d_in[6];

    float* out = (float*)d_out;

    // workspace layout (offsets unchanged from proven rounds)
    char* ws = (char*)d_ws;
    float* x1     = (float*)(ws);                   // 25,600,000 B (+ spill scratch)
    uint4* edata  = (uint4*)(ws + 26000064);        // 19,200,000 B
    int*   bcnt   = (int*)  (ws + 45200064);        //    100,096 B (NBUCK x 64B)
    int*   bbase  = (int*)  (ws + 45300160);        //      6,272 B (NBUCK+1)
    // h[PPART][NBUCK]: carved from the x1 region BEYOND the finalize spill
    // window (spill bytes < 19.2 MB; x1 region is 25.6 MB). Dead before
    // spmm layer 0 overwrites x1. 1,601,536 B @ +19,200,000.
    int*   h      = (int*)  (ws + 19200000);
    const size_t WS_NEEDED = 45406528;

    const int n4 = N_NODES * D / 4;
    const int zb = (n4 + 255) / 256;
    const int fc_blocks = (N_NODES + 63) / 64;            // 1563

    if (ws_size >= WS_NEEDED) {
        zero_ints_kernel<<<(NBUCK * 16 + 255) / 256, 256, 0, stream>>>(bcnt, NBUCK * 16);
        bucket_hist_kernel<<<PPART, 256, 0, stream>>>((const int4*)rows, bcnt, h);
        bucket_scan_kernel<<<1, 256, 0, stream>>>(bcnt, bbase);
        rebase_kernel<<<(NBUCK + 255) / 256, 256, 0, stream>>>(h, bbase);
        partition_kernel<<<PPART, 256, 0, stream>>>(
            (const int4*)rows, (const int4*)cols, (const float4*)vals,
            (const float4*)drop_u, (const float4*)(drop_u + N_EDGES),
            h, edata);
        finalize_kernel<<<NBUCK, 256, 0, stream>>>(edata, bbase, (uint4*)x1);
        // layer 0: x1 = A1 @ all_emb
        spmm_flat_kernel<<<NBUCK, 256, 0, stream>>>(
            (const float4*)all_emb, (const unsigned long long*)edata, bbase,
            (float4*)x1, 0);
        // out = fc(all_emb) + x1
        fc_add_kernel<<<fc_blocks, 256, 0, stream>>>(all_emb, W, b, x1, out);
        // layer 1 (fused /3): out = (out + A2 @ x1) / 3
        spmm_flat_kernel<<<NBUCK, 256, 0, stream>>>(
            (const float4*)x1, (const unsigned long long*)edata, bbase,
            (float4*)out, 1);
    } else {
        // fallback: proven atomic path
        const int spmm_blocks = (N_EDGES + 3) / 4;
        zero_kernel<<<zb, 256, 0, stream>>>((float4*)x1, n4);
        spmm_atomic_kernel<<<spmm_blocks, 256, 0, stream>>>(all_emb, vals, drop_u,
                                                            rows, cols, x1);
        fc_add_kernel<<<fc_blocks, 256, 0, stream>>>(all_emb, W, b, x1, out);
        spmm_atomic_kernel<<<spmm_blocks, 256, 0, stream>>>(x1, vals,
                                                            drop_u + N_EDGES,
                                                            rows, cols, out);
        scale_kernel<<<zb, 256, 0, stream>>>((float4*)out, n4);
    }
}

// Round 8
// 271.631 us; speedup vs baseline: 3.9425x; 1.0355x over previous
//
#include <hip/hip_runtime.h>

#define N_NODES 100000
#define N_EDGES 1200000
#define D 64
#define KEEP_PROB 0.7f
#define INV_KEEP (1.0f / KEEP_PROB)
#define NBUCK 1564         // ceil(N_NODES / 64) row-range buckets (row >> 6)
#define MAXB 1024          // finalize LDS record capacity (mean ~767)
#define PPART 256          // partition/hist blocks (contiguous chunks)
#define CHUNK4 1172        // ceil((N_EDGES/4) / PPART) int4-edges per block
#define NB64 ((NBUCK + 63) / 64)   // 25 blocks for sum/rebase

#define ALOAD_I(p)   __hip_atomic_load((p), __ATOMIC_RELAXED, __HIP_MEMORY_SCOPE_AGENT)
#define ALOAD_U64(p) __hip_atomic_load((p), __ATOMIC_RELAXED, __HIP_MEMORY_SCOPE_AGENT)

// ---------------------------------------------------------------------------
__global__ __launch_bounds__(256) void zero_kernel(float4* __restrict__ p, int n4) {
    int i = blockIdx.x * 256 + threadIdx.x;
    if (i < n4) p[i] = make_float4(0.f, 0.f, 0.f, 0.f);
}

// ---------------------------------------------------------------------------
// Build 1: per-block bucket histogram over CONTIGUOUS chunks (same
// decomposition as partition_kernel). Writes ONLY h[p][b] (coalesced);
// totals now come from sum_kernel (removes 400K contended global atomics).
__global__ __launch_bounds__(256) void bucket_hist_kernel(const int4* __restrict__ rows4,
                                                          int* __restrict__ h) {
    __shared__ int hh[NBUCK];
    int p = blockIdx.x;
    int t = threadIdx.x;
    for (int i = t; i < NBUCK; i += 256) hh[i] = 0;
    __syncthreads();
    int i0 = p * CHUNK4;
    int i1 = i0 + CHUNK4;
    if (i1 > N_EDGES / 4) i1 = N_EDGES / 4;
    for (int i = i0 + t; i < i1; i += 256) {
        int4 r = rows4[i];
        atomicAdd(&hh[r.x >> 6], 1);
        atomicAdd(&hh[r.y >> 6], 1);
        atomicAdd(&hh[r.z >> 6], 1);
        atomicAdd(&hh[r.w >> 6], 1);
    }
    __syncthreads();
    int* hp = h + p * NBUCK;
    for (int i = t; i < NBUCK; i += 256) hp[i] = hh[i];
}

// ---------------------------------------------------------------------------
// Build 1.5: total[b] = sum_p h[p][b]. 64 buckets/block, 4 chunk-threads
// each summing 64 p-entries (coalesced across the 64 adjacent buckets).
__global__ __launch_bounds__(256) void sum_kernel(const int* __restrict__ h,
                                                  int* __restrict__ total) {
    __shared__ int sq[4][64];
    int t = threadIdx.x;
    int bo = t & 63, q = t >> 6;
    int b = blockIdx.x * 64 + bo;
    int s = 0;
    if (b < NBUCK) {
        for (int p = q * 64; p < q * 64 + 64; ++p) s += h[p * NBUCK + b];
    }
    sq[q][bo] = s;
    __syncthreads();
    if (q == 0 && b < NBUCK)
        total[b] = sq[0][bo] + sq[1][bo] + sq[2][bo] + sq[3][bo];
}

// ---------------------------------------------------------------------------
// Build 2: single-block exclusive scan of dense totals -> bbase.
__global__ __launch_bounds__(256) void bucket_scan_kernel(const int* __restrict__ total,
                                                          int* __restrict__ bbase) {
    __shared__ int part[256];
    const int CH = 7;   // 256*7 = 1792 >= NBUCK
    int t = threadIdx.x;
    int e[CH]; int s = 0;
    #pragma unroll
    for (int k = 0; k < CH; ++k) {
        int j = t * CH + k;
        e[k] = (j < NBUCK) ? total[j] : 0;
        s += e[k];
    }
    part[t] = s;
    __syncthreads();
    for (int d = 1; d < 256; d <<= 1) {
        int w = (t >= d) ? part[t - d] : 0;
        __syncthreads();
        part[t] += w;
        __syncthreads();
    }
    int run = part[t] - s;
    #pragma unroll
    for (int k = 0; k < CH; ++k) {
        int j = t * CH + k;
        if (j < NBUCK) { bbase[j] = run; run += e[k]; }
    }
    if (t == 255) bbase[NBUCK] = run;            // == N_EDGES
}

// ---------------------------------------------------------------------------
// Build 2.5 (parallelized — old version was 7 blocks x 256-deep serial):
// h[p][b] <- bbase[b] + sum_{q<p} h[q][b]. 64 buckets/block, 4 chunk-threads
// per bucket: pass-1 chunk sums -> LDS exclusive combine -> pass-2 rewrite.
__global__ __launch_bounds__(256) void rebase_kernel(int* __restrict__ h,
                                                     const int* __restrict__ bbase) {
    __shared__ int sq[4][64];
    int t = threadIdx.x;
    int bo = t & 63, q = t >> 6;
    int b = blockIdx.x * 64 + bo;
    bool ok = (b < NBUCK);
    int s = 0;
    if (ok) {
        for (int p = q * 64; p < q * 64 + 64; ++p) s += h[p * NBUCK + b];
    }
    sq[q][bo] = s;
    __syncthreads();
    if (ok) {
        int run = bbase[b];
        for (int qq = 0; qq < q; ++qq) run += sq[qq][bo];
        for (int p = q * 64; p < q * 64 + 64; ++p) {
            int idx = p * NBUCK + b;
            int c = h[idx];
            h[idx] = run;
            run += c;
        }
    }
}

// ---------------------------------------------------------------------------
// Build 3: partition edges into buckets (R1-proven). Staging record
// (col, v0, v1, row) now lands in the x1 region (dead until spmm layer 0),
// freeing the edata region for the SoA outputs. Atomic-free globally.
__global__ __launch_bounds__(256) void partition_kernel(
    const int4*   __restrict__ rows4,
    const int4*   __restrict__ cols4,
    const float4* __restrict__ vals4,
    const float4* __restrict__ u04,
    const float4* __restrict__ u14,
    const int*    __restrict__ h,
    uint4*        __restrict__ staging) {
    __shared__ int cur[NBUCK];
    int p = blockIdx.x;
    int t = threadIdx.x;
    const int* hp = h + p * NBUCK;
    for (int i = t; i < NBUCK; i += 256) cur[i] = hp[i];
    __syncthreads();

    int i0 = p * CHUNK4;
    int i1 = i0 + CHUNK4;
    if (i1 > N_EDGES / 4) i1 = N_EDGES / 4;
    for (int i = i0 + t; i < i1; i += 256) {
        int4   r  = rows4[i];
        int4   c  = cols4[i];
        float4 v  = vals4[i];
        float4 u0 = u04[i];
        float4 u1 = u14[i];

        int p0 = atomicAdd(&cur[r.x >> 6], 1);
        int p1 = atomicAdd(&cur[r.y >> 6], 1);
        int p2 = atomicAdd(&cur[r.z >> 6], 1);
        int p3 = atomicAdd(&cur[r.w >> 6], 1);

        uint4 rec; float vv;
        vv = v.x * INV_KEEP;
        rec.x = (unsigned)c.x;
        rec.y = __float_as_uint((u0.x + KEEP_PROB >= 1.0f) ? vv : 0.f);
        rec.z = __float_as_uint((u1.x + KEEP_PROB >= 1.0f) ? vv : 0.f);
        rec.w = (unsigned)r.x;
        staging[p0] = rec;
        vv = v.y * INV_KEEP;
        rec.x = (unsigned)c.y;
        rec.y = __float_as_uint((u0.y + KEEP_PROB >= 1.0f) ? vv : 0.f);
        rec.z = __float_as_uint((u1.y + KEEP_PROB >= 1.0f) ? vv : 0.f);
        rec.w = (unsigned)r.y;
        staging[p1] = rec;
        vv = v.z * INV_KEEP;
        rec.x = (unsigned)c.z;
        rec.y = __float_as_uint((u0.z + KEEP_PROB >= 1.0f) ? vv : 0.f);
        rec.z = __float_as_uint((u1.z + KEEP_PROB >= 1.0f) ? vv : 0.f);
        rec.w = (unsigned)r.z;
        staging[p2] = rec;
        vv = v.w * INV_KEEP;
        rec.x = (unsigned)c.w;
        rec.y = __float_as_uint((u0.w + KEEP_PROB >= 1.0f) ? vv : 0.f);
        rec.z = __float_as_uint((u1.w + KEEP_PROB >= 1.0f) ? vv : 0.f);
        rec.w = (unsigned)r.w;
        staging[p3] = rec;
    }
}

// ---------------------------------------------------------------------------
// Build 4: one block per bucket (64 rows). Sort by row, output SoA per-layer
// 8-B records (col|lr<<17, v) into ed0/ed1 — each spmm then fetches only
// its own layer's 9.6 MB (AoS stride-16 reads dragged both layers' lines:
// half of edata's 19.2 MB fetch was waste). Source (staging) and dest are
// DISJOINT now, so the big-bucket path just re-reads global (no spill copy).
__global__ __launch_bounds__(256) void finalize_kernel(
    const uint4* __restrict__ staging,
    const int*   __restrict__ bbase,
    unsigned long long* __restrict__ ed0,
    unsigned long long* __restrict__ ed1) {
    __shared__ uint4 recs[MAXB];
    __shared__ int cnt[64], cur[64], part[64];
    int b = blockIdx.x;
    int t = threadIdx.x;
    int base = bbase[b];
    int size = bbase[b + 1] - base;
    bool small = (size <= MAXB);

    if (small) {
        for (int i = t; i < size; i += 256) recs[i] = staging[base + i];
    }
    if (t < 64) cnt[t] = 0;
    __syncthreads();

    for (int i = t; i < size; i += 256) {
        unsigned rw = small ? recs[i].w : staging[base + i].w;
        atomicAdd(&cnt[rw & 63], 1);
    }
    __syncthreads();

    int v = (t < 64) ? cnt[t] : 0;
    if (t < 64) part[t] = v;
    __syncthreads();
    for (int d = 1; d < 64; d <<= 1) {
        int w = (t >= d && t < 64) ? part[t - d] : 0;
        __syncthreads();
        if (t < 64) part[t] += w;
        __syncthreads();
    }
    if (t < 64) cur[t] = part[t] - v;
    __syncthreads();

    for (int i = t; i < size; i += 256) {
        uint4 r = small ? recs[i] : staging[base + i];
        unsigned lr = r.w & 63u;
        int slot = base + atomicAdd(&cur[lr], 1);
        unsigned cr = r.x | (lr << 17);     // pack local row into col word
        ed0[slot] = ((unsigned long long)r.y << 32) | cr;
        ed1[slot] = ((unsigned long long)r.z << 32) | cr;
    }
}

// ---------------------------------------------------------------------------
// SpMM, flat-balanced register-accumulation (R7-proven structure), now on
// SoA 8-B records. One block per bucket; 16 lane-groups walk contiguous
// ~1/16 slices of the row-sorted edges; register accumulate + plain LDS
// store on row change (ownership protocol; partb merge for slice-boundary
// rows). No LDS atomics (R6 lesson: fp LDS atomicAdd ~3.6 CU-cyc/lane-op).
__global__ __launch_bounds__(256) void spmm_flat_kernel(
    const float4* __restrict__ x_in,
    const unsigned long long* __restrict__ ed,
    const int*   __restrict__ bbase,
    float4*      __restrict__ io,
    int layer) {
    __shared__ float accs[64 * 64];   // 16 KB: [lr][col]
    __shared__ float partb[16][64];   // boundary-prefix partials per group
    __shared__ int   prow[16];
    int b = blockIdx.x;
    int t = threadIdx.x;
    int base = bbase[b];
    int size = bbase[b + 1] - base;
    int row0 = b << 6;

    #pragma unroll
    for (int i = 0; i < 4; ++i)
        *(float4*)&accs[(i * 256 + t) * 4] = make_float4(0.f, 0.f, 0.f, 0.f);
    if (t < 16) prow[t] = -1;
    __syncthreads();

    int g   = t >> 4;                 // lane-group 0..15
    int l16 = t & 15;
    int e0 = base + ((size * g) >> 4);
    int e1 = base + ((size * (g + 1)) >> 4);
    int j0 = l16 << 2;

    // does this slice start mid-row? (prev record has same lr)
    bool partial = false;
    if (e0 < e1 && e0 > base) {
        unsigned plo = (unsigned)ALOAD_U64(&ed[e0 - 1]);
        unsigned flo = (unsigned)ALOAD_U64(&ed[e0]);
        partial = ((plo >> 17) == (flo >> 17));
    }

    float4 acc = make_float4(0.f, 0.f, 0.f, 0.f);
    int cur = -1;
    bool first = true;
    for (int e = e0; e < e1; ++e) {
        unsigned long long rec = ALOAD_U64(&ed[e]);
        unsigned lo = (unsigned)rec;
        float v = __uint_as_float((unsigned)(rec >> 32));
        int lr = (int)(lo >> 17);
        if (lr != cur) {                       // group-uniform branch
            if (cur >= 0) {
                if (first && partial) {
                    *(float4*)&partb[g][j0] = acc;
                    if (l16 == 0) prow[g] = cur;
                } else {
                    *(float4*)&accs[(cur << 6) + j0] = acc;   // owned row
                }
                first = false;
            }
            acc = make_float4(0.f, 0.f, 0.f, 0.f);
            cur = lr;
        }
        int c  = (int)(lo & 0x1ffffu);
        int cc = (v != 0.f) ? c : 0;          // dropped edges -> hot row 0
        float4 x = x_in[(cc << 4) + l16];
        acc.x = fmaf(v, x.x, acc.x);
        acc.y = fmaf(v, x.y, acc.y);
        acc.z = fmaf(v, x.z, acc.z);
        acc.w = fmaf(v, x.w, acc.w);
    }
    if (cur >= 0) {                            // tail flush
        if (first && partial) {
            *(float4*)&partb[g][j0] = acc;
            if (l16 == 0) prow[g] = cur;
        } else {
            *(float4*)&accs[(cur << 6) + j0] = acc;
        }
    }
    __syncthreads();

    // merge boundary partials: 16 lanes, sequential over groups (race-free)
    if (t < 16) {
        int jj = t << 2;
        for (int gg = 1; gg < 16; ++gg) {
            int pr = prow[gg];
            if (pr >= 0) {
                float* a = &accs[(pr << 6) + jj];
                const float* p = &partb[gg][jj];
                a[0] += p[0]; a[1] += p[1]; a[2] += p[2]; a[3] += p[3];
            }
        }
    }
    __syncthreads();

    // writeback: 1024 float4 granules, coalesced
    #pragma unroll
    for (int i = 0; i < 4; ++i) {
        int idx = i * 256 + t;        // 0..1023
        int lr = idx >> 4;
        int gg = idx & 15;
        int row = row0 + lr;
        if (row < N_NODES) {
            float4 sv = *(const float4*)&accs[(lr << 6) + (gg << 2)];
            int o = (row << 4) + gg;
            if (layer == 0) {
                io[o] = sv;
            } else {
                float4 p = io[o];
                p.x = (p.x + sv.x) * (1.0f / 3.0f);
                p.y = (p.y + sv.y) * (1.0f / 3.0f);
                p.z = (p.z + sv.z) * (1.0f / 3.0f);
                p.w = (p.w + sv.w) * (1.0f / 3.0f);
                io[o] = p;
            }
        }
    }
}

// ---------------------------------------------------------------------------
// out[n,j] = b[j] + sum_k emb[n,k]*W[j,k] + x1[n,j]
// Register-blocked: 64 nodes/block, 4x4 tile/thread; launch_bounds(256,4)
// caps VGPR at 128 (R3 lesson: full unroll blew to 240 -> 8.8% occupancy).
#define FMA4(A, E, WV) \
    A.x = fmaf(E, WV.x, A.x); A.y = fmaf(E, WV.y, A.y); \
    A.z = fmaf(E, WV.z, A.z); A.w = fmaf(E, WV.w, A.w);

__global__ __launch_bounds__(256, 4) void fc_add_kernel(
    const float* __restrict__ emb,
    const float* __restrict__ W,
    const float* __restrict__ b,
    const float* __restrict__ x1,
    float*       __restrict__ out) {
    __shared__ float Wt[D * 68];    // Wt[k][j] = W[j][k], row pad 68
    __shared__ float Es[64 * 68];   // Es[n][k],           row pad 68

    int t = threadIdx.x;
    int n0 = blockIdx.x * 64;

    #pragma unroll
    for (int i = 0; i < 16; ++i) {
        int idx = i * 256 + t;          // = j*64 + k
        Wt[(idx & 63) * 68 + (idx >> 6)] = W[idx];
    }
    #pragma unroll
    for (int i = 0; i < 4; ++i) {
        int idx4 = i * 256 + t;
        int n = idx4 >> 4;              // 0..63
        int k0 = (idx4 & 15) * 4;
        float4 v = make_float4(0.f, 0.f, 0.f, 0.f);
        if (n0 + n < N_NODES) v = *(const float4*)&emb[(n0 + n) * D + k0];
        *(float4*)&Es[n * 68 + k0] = v;
    }
    __syncthreads();

    int tj = t & 15;                    // j-group: j0 = 4*tj
    int tn = t >> 4;                    // node-group: nodes 4*tn .. 4*tn+3
    int j0 = tj * 4;

    float4 bb = *(const float4*)&b[j0];
    float4 acc[4];
    #pragma unroll
    for (int i = 0; i < 4; ++i) acc[i] = bb;

    const float* es = &Es[(tn * 4) * 68];
    #pragma unroll 4
    for (int kc = 0; kc < 16; ++kc) {
        int k = kc * 4;
        float4 w0 = *(const float4*)&Wt[(k + 0) * 68 + j0];
        float4 w1 = *(const float4*)&Wt[(k + 1) * 68 + j0];
        float4 w2 = *(const float4*)&Wt[(k + 2) * 68 + j0];
        float4 w3 = *(const float4*)&Wt[(k + 3) * 68 + j0];
        float4 e0 = *(const float4*)&es[0 * 68 + k];
        float4 e1 = *(const float4*)&es[1 * 68 + k];
        float4 e2 = *(const float4*)&es[2 * 68 + k];
        float4 e3 = *(const float4*)&es[3 * 68 + k];
        FMA4(acc[0], e0.x, w0); FMA4(acc[0], e0.y, w1);
        FMA4(acc[0], e0.z, w2); FMA4(acc[0], e0.w, w3);
        FMA4(acc[1], e1.x, w0); FMA4(acc[1], e1.y, w1);
        FMA4(acc[1], e1.z, w2); FMA4(acc[1], e1.w, w3);
        FMA4(acc[2], e2.x, w0); FMA4(acc[2], e2.y, w1);
        FMA4(acc[2], e2.z, w2); FMA4(acc[2], e2.w, w3);
        FMA4(acc[3], e3.x, w0); FMA4(acc[3], e3.y, w1);
        FMA4(acc[3], e3.z, w2); FMA4(acc[3], e3.w, w3);
    }

    #pragma unroll
    for (int i = 0; i < 4; ++i) {
        int n = n0 + tn * 4 + i;
        if (n < N_NODES) {
            float4 p = *(const float4*)&x1[n * D + j0];
            float4 a = acc[i];
            a.x += p.x; a.y += p.y; a.z += p.z; a.w += p.w;
            *(float4*)&out[n * D + j0] = a;
        }
    }
}

// ---------------------------------------------------------------------------
// Fallback (atomic path, replay-proven) if ws too small
__global__ __launch_bounds__(256) void spmm_atomic_kernel(
    const float* __restrict__ x_in,
    const float* __restrict__ vals,
    const float* __restrict__ drop_u,
    const int*   __restrict__ rows,
    const int*   __restrict__ cols,
    float*       __restrict__ x_out) {
    int wave = (blockIdx.x * 256 + threadIdx.x) >> 6;
    int lane = threadIdx.x & 63;
    if (wave >= N_EDGES) return;
    float u = drop_u[wave];
    if (u + KEEP_PROB < 1.0f) return;
    float v = vals[wave] * INV_KEEP;
    atomicAdd(&x_out[rows[wave] * D + lane], v * x_in[cols[wave] * D + lane]);
}

__global__ __launch_bounds__(256) void scale_kernel(float4* __restrict__ p, int n4) {
    int i = blockIdx.x * 256 + threadIdx.x;
    if (i < n4) {
        float4 v = p[i];
        v.x *= (1.f/3.f); v.y *= (1.f/3.f); v.z *= (1.f/3.f); v.w *= (1.f/3.f);
        p[i] = v;
    }
}

// ---------------------------------------------------------------------------
extern "C" void kernel_launch(void* const* d_in, const int* in_sizes, int n_in,
                              void* d_out, int out_size, void* d_ws, size_t ws_size,
                              hipStream_t stream) {
    const float* all_emb = (const float*)d_in[0];
    const float* W       = (const float*)d_in[1];
    const float* b       = (const float*)d_in[2];
    const float* vals    = (const float*)d_in[3];
    const float* drop_u  = (const float*)d_in[4];   // [2, E]
    const int*   rows    = (const int*)d_in[5];
    const int*   cols    = (const int*)d_in[6];

    float* out = (float*)d_out;

    // workspace layout:
    //   [0, 25.6M)       x1 output; staging records live in [0, 19.2M) and
    //                    h[PPART][NBUCK] at +19.2M (both dead before spmm-0
    //                    overwrites the region with x1)
    //   [26.0M, 35.6M)   ed0 — layer-0 SoA 8-B edge records
    //   [35.6M, 45.2M)   ed1 — layer-1 SoA 8-B edge records
    //   then total[], bbase[]
    char* ws = (char*)d_ws;
    float* x1       = (float*)(ws);
    uint4* staging  = (uint4*)(ws);
    int*   h        = (int*)  (ws + 19200000);            // 1,601,536 B
    unsigned long long* ed0 = (unsigned long long*)(ws + 26000064);  // 9.6 MB
    unsigned long long* ed1 = (unsigned long long*)(ws + 35600064);  // 9.6 MB
    int*   total    = (int*)  (ws + 45200064);            // 6,256 B
    int*   bbase    = (int*)  (ws + 45206320);            // 6,272 B
    const size_t WS_NEEDED = 45406528;   // unchanged (proven capacity)

    const int n4 = N_NODES * D / 4;
    const int zb = (n4 + 255) / 256;
    const int fc_blocks = (N_NODES + 63) / 64;            // 1563

    if (ws_size >= WS_NEEDED) {
        bucket_hist_kernel<<<PPART, 256, 0, stream>>>((const int4*)rows, h);
        sum_kernel<<<NB64, 256, 0, stream>>>(h, total);
        bucket_scan_kernel<<<1, 256, 0, stream>>>(total, bbase);
        rebase_kernel<<<NB64, 256, 0, stream>>>(h, bbase);
        partition_kernel<<<PPART, 256, 0, stream>>>(
            (const int4*)rows, (const int4*)cols, (const float4*)vals,
            (const float4*)drop_u, (const float4*)(drop_u + N_EDGES),
            h, staging);
        finalize_kernel<<<NBUCK, 256, 0, stream>>>(staging, bbase, ed0, ed1);
        // layer 0: x1 = A1 @ all_emb   (overwrites staging/h region)
        spmm_flat_kernel<<<NBUCK, 256, 0, stream>>>(
            (const float4*)all_emb, ed0, bbase, (float4*)x1, 0);
        // out = fc(all_emb) + x1
        fc_add_kernel<<<fc_blocks, 256, 0, stream>>>(all_emb, W, b, x1, out);
        // layer 1 (fused /3): out = (out + A2 @ x1) / 3
        spmm_flat_kernel<<<NBUCK, 256, 0, stream>>>(
            (const float4*)x1, ed1, bbase, (float4*)out, 1);
    } else {
        // fallback: proven atomic path
        const int spmm_blocks = (N_EDGES + 3) / 4;
        zero_kernel<<<zb, 256, 0, stream>>>((float4*)x1, n4);
        spmm_atomic_kernel<<<spmm_blocks, 256, 0, stream>>>(all_emb, vals, drop_u,
                                                            rows, cols, x1);
        fc_add_kernel<<<fc_blocks, 256, 0, stream>>>(all_emb, W, b, x1, out);
        spmm_atomic_kernel<<<spmm_blocks, 256, 0, stream>>>(x1, vals,
                                                            drop_u + N_EDGES,
                                                            rows, cols, out);
        scale_kernel<<<zb, 256, 0, stream>>>((float4*)out, n4);
    }
}